// Round 4
// baseline (705.037 us; speedup 1.0000x reference)
//
#include <hip/hip_runtime.h>

typedef int v4i __attribute__((ext_vector_type(4)));

static constexpr int K_DIM = 4096;
static constexpr int BM = 256, BN = 256, BK = 128;
static constexpr int NT = K_DIM / BK;                 // 32 K-tiles

// ---------------- per-token dynamic quantization ----------------
__global__ __launch_bounds__(256) void quant_kernel(const float* __restrict__ x,
                                                    signed char* __restrict__ xq,
                                                    float* __restrict__ xs) {
    const int token = blockIdx.x;
    const float4* row = (const float4*)(x + (size_t)token * K_DIM);
    const int t = threadIdx.x;
    float4 v[4];
    float m = 0.f;
#pragma unroll
    for (int i = 0; i < 4; ++i) {
        v[i] = row[t * 4 + i];
        m = fmaxf(m, fabsf(v[i].x));
        m = fmaxf(m, fabsf(v[i].y));
        m = fmaxf(m, fabsf(v[i].z));
        m = fmaxf(m, fabsf(v[i].w));
    }
#pragma unroll
    for (int d = 32; d > 0; d >>= 1) m = fmaxf(m, __shfl_xor(m, d));
    __shared__ float red[4];
    if ((t & 63) == 0) red[t >> 6] = m;
    __syncthreads();
    const float am = fmaxf(fmaxf(red[0], red[1]), fmaxf(red[2], red[3]));
    const float s = fmaxf(am, 1e-8f) * (1.0f / 127.0f);
    const float inv = 127.0f / fmaxf(am, 1e-8f);

    int pk[4];
#pragma unroll
    for (int i = 0; i < 4; ++i) {
        int q0 = (int)fminf(127.f, fmaxf(-127.f, rintf(v[i].x * inv)));
        int q1 = (int)fminf(127.f, fmaxf(-127.f, rintf(v[i].y * inv)));
        int q2 = (int)fminf(127.f, fmaxf(-127.f, rintf(v[i].z * inv)));
        int q3 = (int)fminf(127.f, fmaxf(-127.f, rintf(v[i].w * inv)));
        pk[i] = (q0 & 255) | ((q1 & 255) << 8) | ((q2 & 255) << 16) | (q3 << 24);
    }
    ((int4*)(xq + (size_t)token * K_DIM))[t] = make_int4(pk[0], pk[1], pk[2], pk[3]);
    if (t == 0) xs[token] = s;
}

// ---------------- weight repack: int32 -> packed int8 ----------------
__global__ __launch_bounds__(256) void repack_kernel(const int* __restrict__ w32,
                                                     int4* __restrict__ w8,
                                                     int n16) {
    const int idx = blockIdx.x * 256 + threadIdx.x;
    if (idx >= n16) return;
    const int4* src = (const int4*)w32 + (size_t)idx * 4;
    int4 a = src[0], b = src[1], c = src[2], d = src[3];
    int p0 = (a.x & 255) | ((a.y & 255) << 8) | ((a.z & 255) << 16) | (a.w << 24);
    int p1 = (b.x & 255) | ((b.y & 255) << 8) | ((b.z & 255) << 16) | (b.w << 24);
    int p2 = (c.x & 255) | ((c.y & 255) << 8) | ((c.z & 255) << 16) | (c.w << 24);
    int p3 = (d.x & 255) | ((d.y & 255) << 8) | ((d.z & 255) << 16) | (d.w << 24);
    w8[idx] = make_int4(p0, p1, p2, p3);
}

// ---- frag loads: R1-verified zero-conflict pattern (128-B rows, col XOR (lane&7)<<4)
#define LOADA(BUF, CX)                                                                \
    _Pragma("unroll") for (int mi = 0; mi < 8; ++mi)                                  \
        a[mi] = *(const v4i*)&sA[BUF][roffA + mi * 2048 + (CX)];
#define LOADB(BUF, NH, CX, DST)                                                       \
    _Pragma("unroll") for (int ni = 0; ni < 2; ++ni)                                  \
        DST[ni] = *(const v4i*)&sB[BUF][roffB + (NH) * 4096 + ni * 2048 + (CX)];
#define MMQ(NH, BF)                                                                   \
    _Pragma("unroll") for (int mi = 0; mi < 8; ++mi)                                  \
    _Pragma("unroll") for (int ni = 0; ni < 2; ++ni)                                  \
        acc[mi][(NH) * 2 + ni] = __builtin_amdgcn_mfma_i32_16x16x64_i8(               \
            a[mi], BF[ni], acc[mi][(NH) * 2 + ni], 0, 0, 0);

// ------- int8 MFMA GEMM, 256x256 tile, front-loaded staging, late boundary drain ----
__global__ __launch_bounds__(512, 2) void gemm_kernel(const signed char* __restrict__ xq,
                                                      const signed char* __restrict__ w8,
                                                      const float* __restrict__ xs,
                                                      const float* __restrict__ scale,
                                                      const float* __restrict__ bias,
                                                      float* __restrict__ out,
                                                      int N) {
    __shared__ __align__(16) signed char sA[2][BM * BK];   // 2 x 32 KB
    __shared__ __align__(16) signed char sB[2][BN * BK];   // 2 x 32 KB

    const int tid = threadIdx.x;
    const int lane = tid & 63;
    const int wid = tid >> 6;          // 8 waves: 2(M) x 4(N)
    const int wm = wid >> 2;
    const int wn = wid & 3;

    // T1: XCD-aware bijective swizzle (grid = 43 x 32 = 1376, divisible by 8)
    const int nwg = gridDim.x * gridDim.y;
    int flat = blockIdx.y * gridDim.x + blockIdx.x;
    if ((nwg & 7) == 0) flat = (flat & 7) * (nwg >> 3) + (flat >> 3);
    const int by = flat % gridDim.y;
    const int bx = flat / gridDim.y;
    const int m0 = by * BM;
    const int n0 = bx * BN;

    v4i acc[8][4];
    const v4i vzero = {0, 0, 0, 0};
#pragma unroll
    for (int i = 0; i < 8; ++i)
#pragma unroll
        for (int j = 0; j < 4; ++j) acc[i][j] = vzero;

    // ---- staging: issue = 512 thr x 16 B = 64 rows x 128 B; write-side inverse swizzle
    // thread tid -> LDS byte tid*16: row = tid>>3, phys slot = tid&7
    // source col within 128-B k-slab = (slot ^ (row&7)) * 16
    const int sswz = (((tid & 7) ^ ((tid >> 3) & 7)) << 4);
    const signed char* srcA = xq + ((size_t)m0 + (tid >> 3)) * K_DIM + sswz;
    const signed char* srcB = w8 + ((size_t)n0 + (tid >> 3)) * K_DIM + sswz;

    // pair: 0 -> issues {0,1} (rows 0-127), 1 -> issues {2,3} (rows 128-255)
    auto stageA = [&](int buf, int pair, int kb) {
#pragma unroll
        for (int ii = 0; ii < 2; ++ii) {
            const int issue = pair * 2 + ii;
            __builtin_amdgcn_global_load_lds(
                (const __attribute__((address_space(1))) void*)(srcA + (size_t)issue * 64 * K_DIM + kb),
                (__attribute__((address_space(3))) void*)&sA[buf][issue * 8192 + wid * 1024],
                16, 0, 0);
        }
    };
    auto stageB = [&](int buf, int pair, int kb) {
#pragma unroll
        for (int ii = 0; ii < 2; ++ii) {
            const int issue = pair * 2 + ii;
            __builtin_amdgcn_global_load_lds(
                (const __attribute__((address_space(1))) void*)(srcB + (size_t)issue * 64 * K_DIM + kb),
                (__attribute__((address_space(3))) void*)&sB[buf][issue * 8192 + wid * 1024],
                16, 0, 0);
        }
    };

    // ---- read-side constants (zero-conflict pattern, measured R1) ----
    const int colx0 = (((lane >> 4) << 4)) ^ ((lane & 7) << 4);   // ks=0
    const int colx1 = colx0 ^ 64;                                  // ks=1
    const int roffA = (wm * 128 + (lane & 15)) * BK;
    const int roffB = (wn * 64 + (lane & 15)) * BK;

    v4i a[8], b[2], b2[2];

    // prologue: stage all of K-tile 0 into buf 0
    stageA(0, 0, 0); stageA(0, 1, 0); stageB(0, 0, 0); stageB(0, 1, 0);
    asm volatile("s_waitcnt vmcnt(0)" ::: "memory");
    __builtin_amdgcn_s_barrier();

    for (int kt = 0; kt < NT - 1; ++kt) {
        const int db = kt & 1;
        const int kb = (kt + 1) * BK;

        // ---- phase 0: reads A(ks0)+B(nh0,ks0); stage A rows 0-127 of kt+1
        LOADA(db, colx0);
        LOADB(db, 0, colx0, b);
        stageA(db ^ 1, 0, kb);
        __builtin_amdgcn_s_barrier();
        asm volatile("s_waitcnt lgkmcnt(0)" ::: "memory");
        __builtin_amdgcn_s_setprio(1);
        MMQ(0, b);
        __builtin_amdgcn_s_setprio(0);
        __builtin_amdgcn_s_barrier();

        // ---- phase 1: reads B(nh1,ks0); stage A rows 128-255
        LOADB(db, 1, colx0, b2);
        stageA(db ^ 1, 1, kb);
        __builtin_amdgcn_s_barrier();
        asm volatile("s_waitcnt lgkmcnt(0)" ::: "memory");
        __builtin_amdgcn_s_setprio(1);
        MMQ(1, b2);
        __builtin_amdgcn_s_setprio(0);
        __builtin_amdgcn_s_barrier();

        // ---- phase 2: reads A(ks1)+B(nh0,ks1); stage B rows 0-127
        LOADA(db, colx1);
        LOADB(db, 0, colx1, b);
        stageB(db ^ 1, 0, kb);
        __builtin_amdgcn_s_barrier();
        asm volatile("s_waitcnt lgkmcnt(0)" ::: "memory");
        __builtin_amdgcn_s_setprio(1);
        MMQ(0, b);
        __builtin_amdgcn_s_setprio(0);
        __builtin_amdgcn_s_barrier();

        // ---- phase 3: reads B(nh1,ks1); stage B rows 128-255; LATE boundary drain
        LOADB(db, 1, colx1, b2);
        stageB(db ^ 1, 1, kb);
        __builtin_amdgcn_s_barrier();
        asm volatile("s_waitcnt lgkmcnt(0)" ::: "memory");
        __builtin_amdgcn_s_setprio(1);
        MMQ(1, b2);
        __builtin_amdgcn_s_setprio(0);
        asm volatile("s_waitcnt vmcnt(0)" ::: "memory");   // youngest load issued ~1 phase ago,
        __builtin_amdgcn_s_barrier();                      // oldest ~4 phases ago
    }

    // ---- last K-tile: everything already drained; no staging
    {
        const int db = (NT - 1) & 1;
        LOADA(db, colx0);
        LOADB(db, 0, colx0, b);
        LOADB(db, 1, colx0, b2);
        asm volatile("s_waitcnt lgkmcnt(0)" ::: "memory");
        __builtin_amdgcn_s_setprio(1);
        MMQ(0, b);
        MMQ(1, b2);
        __builtin_amdgcn_s_setprio(0);
        LOADA(db, colx1);
        LOADB(db, 0, colx1, b);
        LOADB(db, 1, colx1, b2);
        asm volatile("s_waitcnt lgkmcnt(0)" ::: "memory");
        __builtin_amdgcn_s_setprio(1);
        MMQ(0, b);
        MMQ(1, b2);
        __builtin_amdgcn_s_setprio(0);
    }

    // ---- output epilogue: D reg r of lane l -> row (l>>4)*4+r, col l&15 per frag
    const int mrow0 = m0 + wm * 128 + ((lane >> 4) << 2);
    const int ncol0 = n0 + wn * 64 + (lane & 15);
    float xsv[8][4];
#pragma unroll
    for (int mi = 0; mi < 8; ++mi)
#pragma unroll
        for (int r = 0; r < 4; ++r) xsv[mi][r] = xs[mrow0 + mi * 16 + r];

#pragma unroll
    for (int ni = 0; ni < 4; ++ni) {
        const int n = ncol0 + ni * 16;
        const float sc = scale[n];
        const float bs = bias[n];
#pragma unroll
        for (int mi = 0; mi < 8; ++mi) {
#pragma unroll
            for (int r = 0; r < 4; ++r) {
                const int m = mrow0 + mi * 16 + r;
                out[(size_t)m * N + n] = (float)acc[mi][ni][r] * xsv[mi][r] * sc + bs;
            }
        }
    }
}

extern "C" void kernel_launch(void* const* d_in, const int* in_sizes, int n_in,
                              void* d_out, int out_size, void* d_ws, size_t ws_size,
                              hipStream_t stream) {
    const float* x     = (const float*)d_in[0];
    const int*   w32   = (const int*)d_in[1];
    const float* scale = (const float*)d_in[2];
    const float* bias  = (const float*)d_in[3];
    float* out = (float*)d_out;

    const int M = in_sizes[0] / K_DIM;   // 8192
    const int N = in_sizes[2];           // 11008

    char* ws = (char*)d_ws;
    signed char* xq = (signed char*)ws;                                  // M*K
    float* xs = (float*)(ws + (size_t)M * K_DIM);                        // M floats
    signed char* w8 = (signed char*)(ws + (size_t)M * K_DIM + (size_t)M * sizeof(float));  // N*K

    quant_kernel<<<M, 256, 0, stream>>>(x, xq, xs);

    const int n16 = (N * K_DIM) / 16;
    repack_kernel<<<(n16 + 255) / 256, 256, 0, stream>>>(w32, (int4*)w8, n16);

    gemm_kernel<<<dim3(N / BN, M / BM), 512, 0, stream>>>(xq, w8, xs, scale, bias, out, N);
}

// Round 5
// 654.476 us; speedup vs baseline: 1.0773x; 1.0773x over previous
//
#include <hip/hip_runtime.h>

typedef int v4i __attribute__((ext_vector_type(4)));

static constexpr int K_DIM = 4096;
static constexpr int BM = 256, BN = 256, BK = 128;
static constexpr int NT = K_DIM / BK;                 // 32 K-tiles

// ---------------- per-token dynamic quantization ----------------
__global__ __launch_bounds__(256) void quant_kernel(const float* __restrict__ x,
                                                    signed char* __restrict__ xq,
                                                    float* __restrict__ xs) {
    const int token = blockIdx.x;
    const float4* row = (const float4*)(x + (size_t)token * K_DIM);
    const int t = threadIdx.x;
    float4 v[4];
    float m = 0.f;
#pragma unroll
    for (int i = 0; i < 4; ++i) {
        v[i] = row[t * 4 + i];
        m = fmaxf(m, fabsf(v[i].x));
        m = fmaxf(m, fabsf(v[i].y));
        m = fmaxf(m, fabsf(v[i].z));
        m = fmaxf(m, fabsf(v[i].w));
    }
#pragma unroll
    for (int d = 32; d > 0; d >>= 1) m = fmaxf(m, __shfl_xor(m, d));
    __shared__ float red[4];
    if ((t & 63) == 0) red[t >> 6] = m;
    __syncthreads();
    const float am = fmaxf(fmaxf(red[0], red[1]), fmaxf(red[2], red[3]));
    const float s = fmaxf(am, 1e-8f) * (1.0f / 127.0f);
    const float inv = 127.0f / fmaxf(am, 1e-8f);

    int pk[4];
#pragma unroll
    for (int i = 0; i < 4; ++i) {
        int q0 = (int)fminf(127.f, fmaxf(-127.f, rintf(v[i].x * inv)));
        int q1 = (int)fminf(127.f, fmaxf(-127.f, rintf(v[i].y * inv)));
        int q2 = (int)fminf(127.f, fmaxf(-127.f, rintf(v[i].z * inv)));
        int q3 = (int)fminf(127.f, fmaxf(-127.f, rintf(v[i].w * inv)));
        pk[i] = (q0 & 255) | ((q1 & 255) << 8) | ((q2 & 255) << 16) | (q3 << 24);
    }
    ((int4*)(xq + (size_t)token * K_DIM))[t] = make_int4(pk[0], pk[1], pk[2], pk[3]);
    if (t == 0) xs[token] = s;
}

// ---------------- weight repack: int32 -> packed int8 ----------------
__global__ __launch_bounds__(256) void repack_kernel(const int* __restrict__ w32,
                                                     int4* __restrict__ w8,
                                                     int n16) {
    const int idx = blockIdx.x * 256 + threadIdx.x;
    if (idx >= n16) return;
    const int4* src = (const int4*)w32 + (size_t)idx * 4;
    int4 a = src[0], b = src[1], c = src[2], d = src[3];
    int p0 = (a.x & 255) | ((a.y & 255) << 8) | ((a.z & 255) << 16) | (a.w << 24);
    int p1 = (b.x & 255) | ((b.y & 255) << 8) | ((b.z & 255) << 16) | (b.w << 24);
    int p2 = (c.x & 255) | ((c.y & 255) << 8) | ((c.z & 255) << 16) | (c.w << 24);
    int p3 = (d.x & 255) | ((d.y & 255) << 8) | ((d.z & 255) << 16) | (d.w << 24);
    w8[idx] = make_int4(p0, p1, p2, p3);
}

// ---- frag reads: R1/R4-verified zero-conflict pattern (128-B rows, col XOR (lane&7)<<4)
#define RDAL(BUF, CX)                                                                 \
    _Pragma("unroll") for (int mi = 0; mi < 4; ++mi)                                  \
        al[mi] = *(const v4i*)&sA[BUF][roffA + mi * 2048 + (CX)];
#define RDAH(BUF, CX)                                                                 \
    _Pragma("unroll") for (int mi = 0; mi < 4; ++mi)                                  \
        ah[mi] = *(const v4i*)&sA[BUF][roffA + 8192 + mi * 2048 + (CX)];
#define RDB0(BUF, CX)                                                                 \
    _Pragma("unroll") for (int ni = 0; ni < 2; ++ni)                                  \
        b0[ni] = *(const v4i*)&sB[BUF][roffB + ni * 2048 + (CX)];
#define RDB1(BUF, CX)                                                                 \
    _Pragma("unroll") for (int ni = 0; ni < 2; ++ni)                                  \
        b1[ni] = *(const v4i*)&sB[BUF][roffB + 16384 + ni * 2048 + (CX)];
#define MML(NH, BF)                                                                   \
    _Pragma("unroll") for (int mi = 0; mi < 4; ++mi)                                  \
    _Pragma("unroll") for (int ni = 0; ni < 2; ++ni)                                  \
        acc[mi][(NH) * 2 + ni] = __builtin_amdgcn_mfma_i32_16x16x64_i8(               \
            al[mi], BF[ni], acc[mi][(NH) * 2 + ni], 0, 0, 0);
#define MMH(NH, BF)                                                                   \
    _Pragma("unroll") for (int mi = 0; mi < 4; ++mi)                                  \
    _Pragma("unroll") for (int ni = 0; ni < 2; ++ni)                                  \
        acc[4 + mi][(NH) * 2 + ni] = __builtin_amdgcn_mfma_i32_16x16x64_i8(           \
            ah[mi], BF[ni], acc[4 + mi][(NH) * 2 + ni], 0, 0, 0);

// ---- int8 MFMA GEMM, 256x256 tile, unit-split reads + counted-vmcnt pipeline ----
__global__ __launch_bounds__(512, 2) void gemm_kernel(const signed char* __restrict__ xq,
                                                      const signed char* __restrict__ w8,
                                                      const float* __restrict__ xs,
                                                      const float* __restrict__ scale,
                                                      const float* __restrict__ bias,
                                                      float* __restrict__ out,
                                                      int N) {
    __shared__ __align__(16) signed char sA[2][BM * BK];   // 2 x 32 KB
    __shared__ __align__(16) signed char sB[2][BN * BK];   // 2 x 32 KB

    const int tid = threadIdx.x;
    const int lane = tid & 63;
    const int wid = tid >> 6;          // 8 waves: 2(M) x 4(N)
    const int wm = wid >> 2;
    const int wn = wid & 3;

    // T1: XCD-aware bijective swizzle (grid = 43 x 32 = 1376, divisible by 8)
    const int nwg = gridDim.x * gridDim.y;
    int flat = blockIdx.y * gridDim.x + blockIdx.x;
    if ((nwg & 7) == 0) flat = (flat & 7) * (nwg >> 3) + (flat >> 3);
    const int by = flat % gridDim.y;
    const int bx = flat / gridDim.y;
    const int m0 = by * BM;
    const int n0 = bx * BN;

    v4i acc[8][4];
    const v4i vzero = {0, 0, 0, 0};
#pragma unroll
    for (int i = 0; i < 8; ++i)
#pragma unroll
        for (int j = 0; j < 4; ++j) acc[i][j] = vzero;

    // ---- staging sources (per-thread; LDS dest stays linear) ----
    // issue = 512thr x 16B = 64 LDS rows x 128B. thread: row=tid>>3, slot=tid&7,
    // source col = (slot ^ (row&7))*16   [R1/R4 measured-zero-conflict involution]
    const int t8 = tid >> 3;
    const int sswz = (((tid & 7) ^ (t8 & 7)) << 4);
    const signed char* srcA = xq + ((size_t)m0 + t8) * K_DIM + sswz;
    // B row permutation: LDS issues {0,1} hold nh0 rows (wn*64+0..31 for wn=0..3),
    // issues {2,3} hold nh1 rows (wn*64+32..63). Source row for issue 0 + offsets.
    const int gBrow = ((t8 >> 5) << 6) + (t8 & 31);
    const signed char* srcB = w8 + ((size_t)n0 + gBrow) * K_DIM + sswz;

    auto stage6 = [&](int buf, int kb) {   // A-lo issues {0,2} + all B issues
        __builtin_amdgcn_global_load_lds((const __attribute__((address_space(1))) void*)(srcA + kb),
            (__attribute__((address_space(3))) void*)&sA[buf][0 * 8192 + wid * 1024], 16, 0, 0);
        __builtin_amdgcn_global_load_lds((const __attribute__((address_space(1))) void*)(srcA + 128 * K_DIM + kb),
            (__attribute__((address_space(3))) void*)&sA[buf][2 * 8192 + wid * 1024], 16, 0, 0);
        __builtin_amdgcn_global_load_lds((const __attribute__((address_space(1))) void*)(srcB + kb),
            (__attribute__((address_space(3))) void*)&sB[buf][0 * 8192 + wid * 1024], 16, 0, 0);
        __builtin_amdgcn_global_load_lds((const __attribute__((address_space(1))) void*)(srcB + 128 * K_DIM + kb),
            (__attribute__((address_space(3))) void*)&sB[buf][1 * 8192 + wid * 1024], 16, 0, 0);
        __builtin_amdgcn_global_load_lds((const __attribute__((address_space(1))) void*)(srcB + 32 * K_DIM + kb),
            (__attribute__((address_space(3))) void*)&sB[buf][2 * 8192 + wid * 1024], 16, 0, 0);
        __builtin_amdgcn_global_load_lds((const __attribute__((address_space(1))) void*)(srcB + 160 * K_DIM + kb),
            (__attribute__((address_space(3))) void*)&sB[buf][3 * 8192 + wid * 1024], 16, 0, 0);
    };
    auto stage2 = [&](int buf, int kb) {   // A-hi issues {1,3}
        __builtin_amdgcn_global_load_lds((const __attribute__((address_space(1))) void*)(srcA + 64 * K_DIM + kb),
            (__attribute__((address_space(3))) void*)&sA[buf][1 * 8192 + wid * 1024], 16, 0, 0);
        __builtin_amdgcn_global_load_lds((const __attribute__((address_space(1))) void*)(srcA + 192 * K_DIM + kb),
            (__attribute__((address_space(3))) void*)&sA[buf][3 * 8192 + wid * 1024], 16, 0, 0);
    };

    // ---- read-side constants ----
    const int colx0 = ((lane >> 4) << 4) ^ ((lane & 7) << 4);   // ks=0, zero-conflict
    const int colx1 = colx0 ^ 64;                               // ks=1
    const int roffA = (wm * 128 + (lane & 15)) * BK;            // a_lo base; a_hi = +8192
    const int roffB = (wn * 32 + (lane & 15)) * BK;             // nh0 base; nh1 = +16384

    v4i al[4], ah[4], b0[2], b1[2];

    // prologue: tile 0 — 8 issues, publish first 6 (A-lo + all B), keep A-hi in flight
    stage6(0, 0);
    stage2(0, 0);
    asm volatile("s_waitcnt vmcnt(2)" ::: "memory");
    __builtin_amdgcn_s_barrier();

    for (int kt = 0; kt < NT - 1; ++kt) {
        const int db = kt & 1;
        const int kb = (kt + 1) * BK;

        // P0: read a_lo,b0,b1 (ks0); stage6(kt+1); vmcnt(6) covers A-hi(kt)
        RDAL(db, colx0);
        RDB0(db, colx0);
        RDB1(db, colx0);
        stage6(db ^ 1, kb);
        asm volatile("s_waitcnt vmcnt(6)" ::: "memory");
        __builtin_amdgcn_s_barrier();
        asm volatile("s_waitcnt lgkmcnt(0)" ::: "memory");
        __builtin_amdgcn_s_setprio(1);
        MML(0, b0);
        MML(1, b1);
        __builtin_amdgcn_s_setprio(0);
        __builtin_amdgcn_s_barrier();

        // P1: read a_hi (ks0, published at P0 barrier); stage2(kt+1); no wait
        RDAH(db, colx0);
        stage2(db ^ 1, kb);
        __builtin_amdgcn_s_barrier();
        asm volatile("s_waitcnt lgkmcnt(0)" ::: "memory");
        __builtin_amdgcn_s_setprio(1);
        MMH(0, b0);
        MMH(1, b1);
        __builtin_amdgcn_s_setprio(0);
        __builtin_amdgcn_s_barrier();

        // P2: read a_lo,b0,b1 (ks1); no stage, no wait
        RDAL(db, colx1);
        RDB0(db, colx1);
        RDB1(db, colx1);
        __builtin_amdgcn_s_barrier();
        asm volatile("s_waitcnt lgkmcnt(0)" ::: "memory");
        __builtin_amdgcn_s_setprio(1);
        MML(0, b0);
        MML(1, b1);
        __builtin_amdgcn_s_setprio(0);
        __builtin_amdgcn_s_barrier();

        // P3: read a_hi (ks1); vmcnt(2) covers stage6(kt+1) -> publish for next P0
        RDAH(db, colx1);
        asm volatile("s_waitcnt vmcnt(2)" ::: "memory");
        __builtin_amdgcn_s_barrier();
        asm volatile("s_waitcnt lgkmcnt(0)" ::: "memory");
        __builtin_amdgcn_s_setprio(1);
        MMH(0, b0);
        MMH(1, b1);
        __builtin_amdgcn_s_setprio(0);
        __builtin_amdgcn_s_barrier();
    }

    // ---- last K-tile (db=1): only A-hi(NT-1) still in flight -> vmcnt(0) once
    {
        const int db = (NT - 1) & 1;
        RDAL(db, colx0);
        RDB0(db, colx0);
        RDB1(db, colx0);
        asm volatile("s_waitcnt vmcnt(0)" ::: "memory");
        __builtin_amdgcn_s_barrier();
        asm volatile("s_waitcnt lgkmcnt(0)" ::: "memory");
        __builtin_amdgcn_s_setprio(1);
        MML(0, b0);
        MML(1, b1);
        __builtin_amdgcn_s_setprio(0);
        RDAH(db, colx0);
        asm volatile("s_waitcnt lgkmcnt(0)" ::: "memory");
        __builtin_amdgcn_s_setprio(1);
        MMH(0, b0);
        MMH(1, b1);
        __builtin_amdgcn_s_setprio(0);
        RDAL(db, colx1);
        RDB0(db, colx1);
        RDB1(db, colx1);
        asm volatile("s_waitcnt lgkmcnt(0)" ::: "memory");
        __builtin_amdgcn_s_setprio(1);
        MML(0, b0);
        MML(1, b1);
        __builtin_amdgcn_s_setprio(0);
        RDAH(db, colx1);
        asm volatile("s_waitcnt lgkmcnt(0)" ::: "memory");
        __builtin_amdgcn_s_setprio(1);
        MMH(0, b0);
        MMH(1, b1);
        __builtin_amdgcn_s_setprio(0);
    }

    // ---- output epilogue: D reg r of lane l -> row (l>>4)*4+r, col l&15 per frag
    const int mrow0 = m0 + wm * 128 + ((lane >> 4) << 2);
    const int ncol0 = n0 + wn * 64 + (lane & 15);
    float xsv[8][4];
#pragma unroll
    for (int mi = 0; mi < 8; ++mi)
#pragma unroll
        for (int r = 0; r < 4; ++r) xsv[mi][r] = xs[mrow0 + mi * 16 + r];

#pragma unroll
    for (int ni = 0; ni < 4; ++ni) {
        const int n = ncol0 + ni * 16;
        const float sc = scale[n];
        const float bs = bias[n];
#pragma unroll
        for (int mi = 0; mi < 8; ++mi) {
#pragma unroll
            for (int r = 0; r < 4; ++r) {
                const int m = mrow0 + mi * 16 + r;
                out[(size_t)m * N + n] = (float)acc[mi][ni][r] * xsv[mi][r] * sc + bs;
            }
        }
    }
}

extern "C" void kernel_launch(void* const* d_in, const int* in_sizes, int n_in,
                              void* d_out, int out_size, void* d_ws, size_t ws_size,
                              hipStream_t stream) {
    const float* x     = (const float*)d_in[0];
    const int*   w32   = (const int*)d_in[1];
    const float* scale = (const float*)d_in[2];
    const float* bias  = (const float*)d_in[3];
    float* out = (float*)d_out;

    const int M = in_sizes[0] / K_DIM;   // 8192
    const int N = in_sizes[2];           // 11008

    char* ws = (char*)d_ws;
    signed char* xq = (signed char*)ws;                                  // M*K
    float* xs = (float*)(ws + (size_t)M * K_DIM);                        // M floats
    signed char* w8 = (signed char*)(ws + (size_t)M * K_DIM + (size_t)M * sizeof(float));  // N*K

    quant_kernel<<<M, 256, 0, stream>>>(x, xq, xs);

    const int n16 = (N * K_DIM) / 16;
    repack_kernel<<<(n16 + 255) / 256, 256, 0, stream>>>(w32, (int4*)w8, n16);

    gemm_kernel<<<dim3(N / BN, M / BM), 512, 0, stream>>>(xq, w8, xs, scale, bias, out, N);
}